// Round 13
// baseline (122.491 us; speedup 1.0000x reference)
//
#include <hip/hip_runtime.h>
#include <hip/hip_bf16.h>
#include <math.h>

#define D_MODEL 1024
#define D_STATE 16
#define D_CONV  4
#define D_INNER 2048
#define DT_RANK 64
#define B_SZ    4
#define L_SEQ   2048

// d_out layout (floats): dt | A | B | C | x
#define OFF_DT 0
#define OFF_A  (B_SZ * D_INNER * L_SEQ)
#define OFF_B  (OFF_A + D_INNER * D_STATE)
#define OFF_C  (OFF_B + B_SZ * D_STATE * L_SEQ)
#define OFF_X  (OFF_C + B_SZ * D_STATE * L_SEQ)

typedef __attribute__((ext_vector_type(8))) short bf16x8;
typedef __attribute__((ext_vector_type(8))) unsigned short us8;
typedef __attribute__((ext_vector_type(4))) float f32x4;
typedef unsigned short ushort_t;
typedef unsigned int uint_t;

static __device__ __forceinline__ ushort_t f2bf(float f) {
  __hip_bfloat16 h = __float2bfloat16(f);
  return *(ushort_t*)&h;
}
static __device__ __forceinline__ float bf2f(ushort_t u) {
  union { uint_t u; float f; } c;
  c.u = ((uint_t)u) << 16;
  return c.f;
}

// ---------------------------------------------------------------------------
// K0: fused prep — bf16 casts (hs, in_proj x-half, x_proj_w, dt_proj_w) and
// A = -exp(A_log). No zeroing needed anymore (split-K uses partial buffers).
// ---------------------------------------------------------------------------
#define N4_HS   (B_SZ * L_SEQ * D_MODEL / 4)                 // 2097152
#define N4_W    (D_INNER * D_MODEL / 4)                      // 524288
#define N4_XW   ((DT_RANK + 2 * D_STATE) * D_INNER / 4)      // 49152
#define N4_DW   (D_INNER * DT_RANK / 4)                      // 32768
#define N4_A    (D_INNER * D_STATE / 4)                      // 8192   (A)
#define N4_TOT  (N4_HS + N4_W + N4_XW + N4_DW + N4_A)

__global__ __launch_bounds__(256) void k_prep(
    const float4* __restrict__ hs, const float4* __restrict__ ipw,
    const float4* __restrict__ xpw, const float4* __restrict__ dpw,
    const float4* __restrict__ alog,
    ushort4* __restrict__ bfHS, ushort4* __restrict__ bfW,
    ushort4* __restrict__ xwb, ushort4* __restrict__ dwb,
    float4* __restrict__ aout) {
  int i = blockIdx.x * 256 + threadIdx.x;
  if (i < N4_HS) {
    float4 v = hs[i];
    ushort4 o; o.x = f2bf(v.x); o.y = f2bf(v.y); o.z = f2bf(v.z); o.w = f2bf(v.w);
    bfHS[i] = o;
    return;
  }
  i -= N4_HS;
  if (i < N4_W) {
    float4 v = ipw[i];
    ushort4 o; o.x = f2bf(v.x); o.y = f2bf(v.y); o.z = f2bf(v.z); o.w = f2bf(v.w);
    bfW[i] = o;
    return;
  }
  i -= N4_W;
  if (i < N4_XW) {
    float4 v = xpw[i];
    ushort4 o; o.x = f2bf(v.x); o.y = f2bf(v.y); o.z = f2bf(v.z); o.w = f2bf(v.w);
    xwb[i] = o;
    return;
  }
  i -= N4_XW;
  if (i < N4_DW) {
    float4 v = dpw[i];
    ushort4 o; o.x = f2bf(v.x); o.y = f2bf(v.y); o.z = f2bf(v.z); o.w = f2bf(v.w);
    dwb[i] = o;
    return;
  }
  i -= N4_DW;
  if (i < N4_A) {
    float4 v = alog[i];
    float4 o;
    o.x = -expf(v.x); o.y = -expf(v.y); o.z = -expf(v.z); o.w = -expf(v.w);
    aout[i] = o;
  }
}

// ---------------------------------------------------------------------------
// K1: in_proj (x half) via bf16 MFMA — 256x256 tile, BK=64, 512 thr / 8 waves.
// Counted-vmcnt 2-deep pipeline + T5 setprio + LDS-staged 2-panel epilogue.
// (unchanged from round 12)
// ---------------------------------------------------------------------------
__global__ __launch_bounds__(512, 2) void k_inproj_mfma(
    const ushort_t* __restrict__ Wb,   // [D_INNER][D_MODEL] bf16
    const ushort_t* __restrict__ HSb,  // [B][L][D_MODEL] bf16
    ushort_t* __restrict__ Cout) {     // [B][D_INNER][L] bf16
  const int flat = blockIdx.x + 8 * blockIdx.y + 64 * blockIdx.z;
  const int swz  = (flat & 7) * 32 + (flat >> 3);
  const int bn = swz & 7;
  const int bm = (swz >> 3) & 7;
  const int b  = swz >> 6;

  __shared__ ushort_t sh[65536];  // 128 KB
  const int tid  = threadIdx.x;
  const int w    = tid >> 6;
  const int lane = tid & 63;
  const int wm = w >> 2, wn = w & 3;
  const int ksel = lane >> 4;
  const int frow = lane & 15;
  const int sr = tid >> 2;
  const int ss = tid & 3;

  const ushort_t* Ag = Wb + (size_t)(bm * 256) * D_MODEL;
  const ushort_t* Bg = HSb + (size_t)b * L_SEQ * D_MODEL
                           + (size_t)(bn * 256) * D_MODEL;

  f32x4 acc[8][4];
#pragma unroll
  for (int m = 0; m < 8; ++m)
#pragma unroll
    for (int n = 0; n < 4; ++n) acc[m][n] = (f32x4){0.f, 0.f, 0.f, 0.f};

  const int sxs = ss ^ ((sr >> 1) & 3);

#define STAGE(BUF, T)                                                            \
  do {                                                                           \
    _Pragma("unroll")                                                            \
    for (int mh = 0; mh < 4; ++mh) {                                             \
      const ushort_t* gbase = (mh < 2) ? Ag : Bg;                                \
      const ushort_t* grow = gbase + (size_t)((mh & 1) * 128 + sr) * D_MODEL     \
                                   + (T) * 64 + sxs * 8;                         \
      _Pragma("unroll")                                                          \
      for (int q = 0; q < 2; ++q) {                                              \
        ushort_t* dst = sh + (BUF) * 32768 + (mh >> 1) * 16384                   \
                           + (mh & 1) * 8192 + q * 4096 + tid * 8;               \
        __builtin_amdgcn_global_load_lds(                                        \
            (const __attribute__((address_space(1))) void*)(grow + q * 32),      \
            (__attribute__((address_space(3))) void*)dst, 16, 0, 0);             \
      }                                                                          \
    }                                                                            \
  } while (0)

#define COMPUTE(BUF)                                                             \
  do {                                                                           \
    _Pragma("unroll")                                                            \
    for (int ks = 0; ks < 2; ++ks) {                                             \
      bf16x8 af[8], bfr[4];                                                      \
      _Pragma("unroll")                                                          \
      for (int m = 0; m < 8; ++m) {                                              \
        int r = m * 16 + frow;                                                   \
        af[m] = *(const bf16x8*)(sh + (BUF) * 32768 + wm * 8192 + ks * 4096      \
                                 + (r * 4 + (ksel ^ ((r >> 1) & 3))) * 8);       \
      }                                                                          \
      _Pragma("unroll")                                                          \
      for (int n = 0; n < 4; ++n) {                                              \
        int ll = wn * 64 + n * 16 + frow;                                        \
        int h = ll >> 7, r = ll & 127;                                           \
        bfr[n] = *(const bf16x8*)(sh + (BUF) * 32768 + 16384 + h * 8192          \
                                  + ks * 4096                                    \
                                  + (r * 4 + (ksel ^ ((r >> 1) & 3))) * 8);      \
      }                                                                          \
      __builtin_amdgcn_s_setprio(1);                                             \
      _Pragma("unroll")                                                          \
      for (int m = 0; m < 8; ++m)                                                \
        _Pragma("unroll")                                                        \
        for (int n = 0; n < 4; ++n)                                              \
          acc[m][n] = __builtin_amdgcn_mfma_f32_16x16x32_bf16(af[m], bfr[n],     \
                                                              acc[m][n], 0, 0, 0); \
      __builtin_amdgcn_s_setprio(0);                                             \
    }                                                                            \
  } while (0)

  STAGE(0, 0);
  STAGE(1, 1);
  asm volatile("s_waitcnt vmcnt(8)" ::: "memory");
  __builtin_amdgcn_s_barrier();

  for (int t = 0; t < 14; ++t) {
    COMPUTE(t & 1);
    __builtin_amdgcn_sched_barrier(0);
    __builtin_amdgcn_s_barrier();
    STAGE(t & 1, t + 2);
    asm volatile("s_waitcnt vmcnt(8)" ::: "memory");
    __builtin_amdgcn_s_barrier();
    __builtin_amdgcn_sched_barrier(0);
  }
  COMPUTE(0);
  __builtin_amdgcn_sched_barrier(0);
  __builtin_amdgcn_s_barrier();
  asm volatile("s_waitcnt vmcnt(0)" ::: "memory");
  __builtin_amdgcn_s_barrier();
  COMPUTE(1);
#undef STAGE
#undef COMPUTE

  __syncthreads();

  const int crow0 = (lane >> 4) * 4;
  const int ccol  = lane & 15;
  ushort_t* Cb = Cout + (size_t)b * D_INNER * L_SEQ;
#pragma unroll
  for (int p = 0; p < 2; ++p) {
    if (wm == p) {
#pragma unroll
      for (int m = 0; m < 8; ++m)
#pragma unroll
        for (int n = 0; n < 4; ++n) {
          int r0 = m * 16 + crow0;
          int c  = wn * 64 + n * 16 + ccol;
#pragma unroll
          for (int i = 0; i < 4; ++i)
            sh[(r0 + i) * 272 + c] = f2bf(acc[m][n][i]);
        }
    }
    __syncthreads();
#pragma unroll
    for (int q = 0; q < 8; ++q) {
      int idx = q * 512 + tid;
      int r   = idx >> 5;
      int c8  = idx & 31;
      us8 v = *(const us8*)(sh + r * 272 + c8 * 8);
      *(us8*)(Cb + (size_t)(bm * 256 + p * 128 + r) * L_SEQ + bn * 256 + c8 * 8) = v;
    }
    __syncthreads();
  }
}

// ---------------------------------------------------------------------------
// K3: x_proj via bf16 MFMA + fused conv4+SiLU. Split-K 4, N-tile 64.
// THIS ROUND: atomic-free epilogue — partials to PX[sk][b][64][L] and
// PBC[sk][b][32][L] (B rows 0-15, C rows 16-31); reduced in k_dt_mfma.
// ---------------------------------------------------------------------------
__global__ __launch_bounds__(256) void k_xproj_fused(
    const ushort_t* __restrict__ XWb,  // [96][2048] bf16
    const ushort_t* __restrict__ Xpre, // [B][D_INNER][L] bf16 (pre-conv)
    const float* __restrict__ CW,      // [D_INNER][4] conv weights
    const float* __restrict__ CB,      // [D_INNER] conv bias
    float* __restrict__ Xout,          // [B][D_INNER][L] fp32 (post conv+silu)
    float* __restrict__ PX,            // [4 sk][B][64][L] fp32 partials
    float* __restrict__ PBC) {         // [4 sk][B][32][L] fp32 partials (B|C)
  const int ln = blockIdx.x;   // 0..31 (l-tile of 64)
  const int sk = blockIdx.y;   // 0..3  (d-range of 512)
  const int b  = blockIdx.z;
  __shared__ ushort_t As[96 * 40];
  __shared__ ushort_t Bs[64 * 34];
  const int tid  = threadIdx.x;
  const int wv   = tid >> 6;
  const int lane = tid & 63;
  const int wr = wv >> 1, wc = wv & 1;
  const int ksel = lane >> 4;
  const int frow = lane & 15;

  f32x4 acc[3][2];
#pragma unroll
  for (int i = 0; i < 3; ++i)
#pragma unroll
    for (int j = 0; j < 2; ++j) acc[i][j] = (f32x4){0.f, 0.f, 0.f, 0.f};

  for (int k0 = 0; k0 < 512; k0 += 32) {
    const int koff = sk * 512 + k0;
    // ---- stage A tile [96][32] ----
    {
      int row = tid >> 2, s = tid & 3;
      bf16x8 v = *(const bf16x8*)(XWb + (size_t)row * D_INNER + koff + s * 8);
      *(bf16x8*)(As + row * 40 + s * 8) = v;
      if (tid < 128) {
        int row2 = 64 + (tid >> 2);
        bf16x8 v2 = *(const bf16x8*)(XWb + (size_t)row2 * D_INNER + koff + s * 8);
        *(bf16x8*)(As + row2 * 40 + s * 8) = v2;
      }
    }
    // ---- stage B tile [32 d][64 l]: 256 tasks, one per thread ----
    {
      int n4 = tid & 15;
      int kp = tid >> 4;
      int l0 = ln * 64 + 4 * n4;
      float sv[2][4];
#pragma unroll
      for (int r = 0; r < 2; ++r) {
        int d = koff + 2 * kp + r;
        const ushort_t* row = Xpre + ((size_t)b * D_INNER + d) * L_SEQ;
        ushort4 cur = *(const ushort4*)(row + l0);
        float em3 = 0.f, em2 = 0.f, em1 = 0.f;
        if (l0 >= 4) {
          ushort4 pv = *(const ushort4*)(row + l0 - 4);
          em3 = bf2f(pv.y); em2 = bf2f(pv.z); em1 = bf2f(pv.w);
        }
        float ee[7] = {em3, em2, em1, bf2f(cur.x), bf2f(cur.y), bf2f(cur.z), bf2f(cur.w)};
        float4 w = *(const float4*)(CW + d * 4);
        float bias = CB[d];
#pragma unroll
        for (int i = 0; i < 4; ++i) {
          float v = w.x * ee[i] + w.y * ee[i + 1] + w.z * ee[i + 2] + w.w * ee[i + 3] + bias;
          sv[r][i] = v / (1.f + expf(-v));
        }
        *(float4*)(Xout + ((size_t)b * D_INNER + d) * L_SEQ + l0) =
            make_float4(sv[r][0], sv[r][1], sv[r][2], sv[r][3]);
      }
#pragma unroll
      for (int i = 0; i < 4; ++i) {
        uint_t pk = (uint_t)f2bf(sv[0][i]) | ((uint_t)f2bf(sv[1][i]) << 16);
        *(uint_t*)(Bs + (4 * n4 + i) * 34 + 2 * kp) = pk;
      }
    }
    __syncthreads();

    // ---- fragments ----
    bf16x8 af[3], bfr[2];
#pragma unroll
    for (int mi = 0; mi < 3; ++mi) {
      int row = wr * 48 + mi * 16 + frow;
      af[mi] = *(const bf16x8*)(As + row * 40 + ksel * 8);
    }
#pragma unroll
    for (int ni = 0; ni < 2; ++ni) {
      int n = wc * 32 + ni * 16 + frow;
      const uint_t* p = (const uint_t*)(Bs + n * 34);
      union { uint_t u[4]; bf16x8 v; } fr;
#pragma unroll
      for (int q = 0; q < 4; ++q) fr.u[q] = p[ksel * 4 + q];
      bfr[ni] = fr.v;
    }
#pragma unroll
    for (int mi = 0; mi < 3; ++mi)
#pragma unroll
      for (int ni = 0; ni < 2; ++ni)
        acc[mi][ni] = __builtin_amdgcn_mfma_f32_16x16x32_bf16(af[mi], bfr[ni], acc[mi][ni], 0, 0, 0);
    __syncthreads();
  }

  // ---- epilogue: plain stores to partial buffers (wave-uniform per wr,mi) ----
  const int crow0 = (lane >> 4) * 4;
  const int ccol  = lane & 15;
#pragma unroll
  for (int mi = 0; mi < 3; ++mi) {
    int e0 = wr * 48 + mi * 16 + crow0;
    float* base;
    int eoff;
    if (e0 < 64) { base = PX  + ((size_t)(sk * B_SZ + b) * 64) * L_SEQ; eoff = e0; }
    else         { base = PBC + ((size_t)(sk * B_SZ + b) * 32) * L_SEQ; eoff = e0 - 64; }
#pragma unroll
    for (int ni = 0; ni < 2; ++ni) {
      int l = ln * 64 + wc * 32 + ni * 16 + ccol;
#pragma unroll
      for (int r = 0; r < 4; ++r)
        base[(size_t)(eoff + r) * L_SEQ + l] = acc[mi][ni][r];
    }
  }
}

// ---------------------------------------------------------------------------
// K4: dt GEMM via bf16 MFMA + split-K reduction. B-staging sums the 4 PX
// partials while packing bf16; dm==0 blocks also reduce PBC -> B/C outputs.
// ---------------------------------------------------------------------------
__global__ __launch_bounds__(256) void k_dt_mfma(
    const ushort_t* __restrict__ DWb,  // [D_INNER][64] bf16
    const float* __restrict__ PX,      // [4][B][64][L] fp32 partials
    const float* __restrict__ PBC,     // [4][B][32][L] fp32 partials
    float* __restrict__ DT,            // [B][D_INNER][L] fp32
    float* __restrict__ OutB,          // [B][16][L]
    float* __restrict__ OutC) {        // [B][16][L]
  const int ln = blockIdx.x;   // 0..15 (l tile)
  const int dm = blockIdx.y;   // 0..15 (d tile)
  const int b  = blockIdx.z;
  __shared__ ushort_t As[128 * 72];
  __shared__ ushort_t Bs[128 * 68];
  const int tid  = threadIdx.x;
  const int wv   = tid >> 6;
  const int lane = tid & 63;
  const int wr = wv >> 1, wc = wv & 1;
  const int ksel = lane >> 4;
  const int frow = lane & 15;

#pragma unroll
  for (int q = 0; q < 4; ++q) {
    int u = tid + 256 * q;
    int row = u >> 3, s = u & 7;
    *(bf16x8*)(As + row * 72 + s * 8) =
        *(const bf16x8*)(DWb + (size_t)(dm * 128 + row) * DT_RANK + s * 8);
  }
#pragma unroll
  for (int q = 0; q < 4; ++q) {
    int u = tid + 256 * q;
    int n4 = u & 31;
    int kp = u >> 5;
    float4 x0 = {0.f, 0.f, 0.f, 0.f}, x1 = {0.f, 0.f, 0.f, 0.f};
#pragma unroll
    for (int sk = 0; sk < 4; ++sk) {
      const float* g = PX + ((size_t)(sk * B_SZ + b) * 64 + 2 * kp) * L_SEQ
                          + ln * 128 + 4 * n4;
      float4 a0 = *(const float4*)g;
      float4 a1 = *(const float4*)(g + L_SEQ);
      x0.x += a0.x; x0.y += a0.y; x0.z += a0.z; x0.w += a0.w;
      x1.x += a1.x; x1.y += a1.y; x1.z += a1.z; x1.w += a1.w;
    }
    float e0[4] = {x0.x, x0.y, x0.z, x0.w};
    float e1[4] = {x1.x, x1.y, x1.z, x1.w};
#pragma unroll
    for (int i = 0; i < 4; ++i) {
      uint_t pk = (uint_t)f2bf(e0[i]) | ((uint_t)f2bf(e1[i]) << 16);
      *(uint_t*)(Bs + (4 * n4 + i) * 68 + 2 * kp) = pk;
    }
  }
  __syncthreads();

  f32x4 acc[4][4];
#pragma unroll
  for (int i = 0; i < 4; ++i)
#pragma unroll
    for (int j = 0; j < 4; ++j) acc[i][j] = (f32x4){0.f, 0.f, 0.f, 0.f};

#pragma unroll
  for (int ks = 0; ks < 2; ++ks) {
    bf16x8 af[4], bfr[4];
#pragma unroll
    for (int m = 0; m < 4; ++m) {
      int row = wr * 64 + m * 16 + frow;
      af[m] = *(const bf16x8*)(As + row * 72 + ks * 32 + ksel * 8);
    }
#pragma unroll
    for (int n = 0; n < 4; ++n) {
      int nn = wc * 64 + n * 16 + frow;
      bfr[n] = *(const bf16x8*)(Bs + nn * 68 + ks * 32 + ksel * 8);
    }
#pragma unroll
    for (int m = 0; m < 4; ++m)
#pragma unroll
      for (int n = 0; n < 4; ++n)
        acc[m][n] = __builtin_amdgcn_mfma_f32_16x16x32_bf16(af[m], bfr[n], acc[m][n], 0, 0, 0);
  }

  const int crow0 = (lane >> 4) * 4;
  const int ccol  = lane & 15;
  float* Cb = DT + (size_t)b * D_INNER * L_SEQ;
#pragma unroll
  for (int m = 0; m < 4; ++m) {
    int gr0 = dm * 128 + wr * 64 + m * 16 + crow0;
#pragma unroll
    for (int n = 0; n < 4; ++n) {
      int gc = ln * 128 + wc * 64 + n * 16 + ccol;
#pragma unroll
      for (int i = 0; i < 4; ++i)
        Cb[(size_t)(gr0 + i) * L_SEQ + gc] = acc[m][n][i];
    }
  }

  // ---- B/C partial reduction (dm == 0 blocks only) ----
  if (dm == 0) {
#pragma unroll
    for (int q = 0; q < 4; ++q) {
      int u = tid + 256 * q;       // 0..1023
      int e  = u >> 5;             // 0..31 (0-15 B, 16-31 C)
      int c4 = u & 31;             // float4 chunk within 128 l
      int l0 = ln * 128 + c4 * 4;
      float4 s = {0.f, 0.f, 0.f, 0.f};
#pragma unroll
      for (int sk = 0; sk < 4; ++sk) {
        float4 p = *(const float4*)(PBC + ((size_t)(sk * B_SZ + b) * 32 + e) * L_SEQ + l0);
        s.x += p.x; s.y += p.y; s.z += p.z; s.w += p.w;
      }
      if (e < 16)
        *(float4*)(OutB + ((size_t)b * D_STATE + e) * L_SEQ + l0) = s;
      else
        *(float4*)(OutC + ((size_t)b * D_STATE + (e - 16)) * L_SEQ + l0) = s;
    }
  }
}

extern "C" void kernel_launch(void* const* d_in, const int* in_sizes, int n_in,
                              void* d_out, int out_size, void* d_ws, size_t ws_size,
                              hipStream_t stream) {
  const float* hs   = (const float*)d_in[0];
  const float* ipw  = (const float*)d_in[1];
  const float* cw   = (const float*)d_in[2];
  const float* cb   = (const float*)d_in[3];
  const float* xpw  = (const float*)d_in[4];
  const float* dpw  = (const float*)d_in[5];
  const float* alog = (const float*)d_in[6];

  float* out    = (float*)d_out;
  float* dt_out = out + OFF_DT;
  float* a_out  = out + OFF_A;
  float* b_out  = out + OFF_B;
  float* c_out  = out + OFF_C;
  float* x_out  = out + OFF_X;

  // Scratch plan:
  //  - bf16 HS (16.8 MB) + bf16 W-half (4.2 MB) in x region of d_out.
  //  - xpre (bf16, 33.5 MB) in dt region (dead after xproj; dt overwrites).
  //  - d_ws: PX 8 MB | PBC 4 MB | XWb 384 KB | DWb 256 KB.
  unsigned short* bfHS = (unsigned short*)x_out;
  unsigned short* bfW  = bfHS + (size_t)B_SZ * L_SEQ * D_MODEL;
  unsigned short* xpre = (unsigned short*)dt_out;
  float* px  = (float*)d_ws;                                   // 8 MB
  float* pbc = (float*)((char*)d_ws + 8388608);                // 4 MB
  unsigned short* xwb = (unsigned short*)((char*)d_ws + 8388608 + 4194304);
  unsigned short* dwb = (unsigned short*)((char*)d_ws + 8388608 + 4194304 + 393216);

  // One fused prep launch: 4 casts + A = -exp(A_log). (No zeroing needed.)
  k_prep<<<dim3((N4_TOT + 255) / 256), 256, 0, stream>>>(
      (const float4*)hs, (const float4*)ipw, (const float4*)xpw,
      (const float4*)dpw, (const float4*)alog,
      (ushort4*)bfHS, (ushort4*)bfW, (ushort4*)xwb, (ushort4*)dwb,
      (float4*)a_out);

  k_inproj_mfma<<<dim3(8, 8, 4), 512, 0, stream>>>(bfW, bfHS, xpre);
  k_xproj_fused<<<dim3(32, 4, 4), 256, 0, stream>>>(xwb, xpre, cw, cb,
                                                    x_out, px, pbc);
  k_dt_mfma<<<dim3(16, 16, 4), 256, 0, stream>>>(dwb, px, pbc, dt_out,
                                                 b_out, c_out);
}

// Round 14
// 119.556 us; speedup vs baseline: 1.0246x; 1.0246x over previous
//
#include <hip/hip_runtime.h>
#include <hip/hip_bf16.h>
#include <math.h>

#define D_MODEL 1024
#define D_STATE 16
#define D_CONV  4
#define D_INNER 2048
#define DT_RANK 64
#define B_SZ    4
#define L_SEQ   2048

// d_out layout (floats): dt | A | B | C | x
#define OFF_DT 0
#define OFF_A  (B_SZ * D_INNER * L_SEQ)
#define OFF_B  (OFF_A + D_INNER * D_STATE)
#define OFF_C  (OFF_B + B_SZ * D_STATE * L_SEQ)
#define OFF_X  (OFF_C + B_SZ * D_STATE * L_SEQ)

typedef __attribute__((ext_vector_type(8))) short bf16x8;
typedef __attribute__((ext_vector_type(8))) unsigned short us8;
typedef __attribute__((ext_vector_type(4))) float f32x4;
typedef unsigned short ushort_t;
typedef unsigned int uint_t;

static __device__ __forceinline__ ushort_t f2bf(float f) {
  __hip_bfloat16 h = __float2bfloat16(f);
  return *(ushort_t*)&h;
}
static __device__ __forceinline__ float bf2f(ushort_t u) {
  union { uint_t u; float f; } c;
  c.u = ((uint_t)u) << 16;
  return c.f;
}

// ---------------------------------------------------------------------------
// K0: fused prep — bf16 casts (hs, in_proj x-half, x_proj_w, dt_proj_w),
// zero split-K targets (xdbl, B|C), and A = -exp(A_log). One launch.
// ---------------------------------------------------------------------------
#define N4_HS   (B_SZ * L_SEQ * D_MODEL / 4)                 // 2097152
#define N4_W    (D_INNER * D_MODEL / 4)                      // 524288
#define N4_XW   ((DT_RANK + 2 * D_STATE) * D_INNER / 4)      // 49152
#define N4_DW   (D_INNER * DT_RANK / 4)                      // 32768
#define N4_Z0   (B_SZ * DT_RANK * L_SEQ / 4)                 // 131072 (xdbl)
#define N4_Z1   (2 * B_SZ * D_STATE * L_SEQ / 4)             // 65536  (B|C)
#define N4_A    (D_INNER * D_STATE / 4)                      // 8192   (A)
#define N4_TOT  (N4_HS + N4_W + N4_XW + N4_DW + N4_Z0 + N4_Z1 + N4_A)

__global__ __launch_bounds__(256) void k_prep(
    const float4* __restrict__ hs, const float4* __restrict__ ipw,
    const float4* __restrict__ xpw, const float4* __restrict__ dpw,
    const float4* __restrict__ alog,
    ushort4* __restrict__ bfHS, ushort4* __restrict__ bfW,
    ushort4* __restrict__ xwb, ushort4* __restrict__ dwb,
    float4* __restrict__ z0, float4* __restrict__ z1,
    float4* __restrict__ aout) {
  int i = blockIdx.x * 256 + threadIdx.x;
  if (i < N4_HS) {
    float4 v = hs[i];
    ushort4 o; o.x = f2bf(v.x); o.y = f2bf(v.y); o.z = f2bf(v.z); o.w = f2bf(v.w);
    bfHS[i] = o;
    return;
  }
  i -= N4_HS;
  if (i < N4_W) {
    float4 v = ipw[i];
    ushort4 o; o.x = f2bf(v.x); o.y = f2bf(v.y); o.z = f2bf(v.z); o.w = f2bf(v.w);
    bfW[i] = o;
    return;
  }
  i -= N4_W;
  if (i < N4_XW) {
    float4 v = xpw[i];
    ushort4 o; o.x = f2bf(v.x); o.y = f2bf(v.y); o.z = f2bf(v.z); o.w = f2bf(v.w);
    xwb[i] = o;
    return;
  }
  i -= N4_XW;
  if (i < N4_DW) {
    float4 v = dpw[i];
    ushort4 o; o.x = f2bf(v.x); o.y = f2bf(v.y); o.z = f2bf(v.z); o.w = f2bf(v.w);
    dwb[i] = o;
    return;
  }
  i -= N4_DW;
  if (i < N4_Z0) { z0[i] = (float4){0.f, 0.f, 0.f, 0.f}; return; }
  i -= N4_Z0;
  if (i < N4_Z1) { z1[i] = (float4){0.f, 0.f, 0.f, 0.f}; return; }
  i -= N4_Z1;
  if (i < N4_A) {
    float4 v = alog[i];
    float4 o;
    o.x = -expf(v.x); o.y = -expf(v.y); o.z = -expf(v.z); o.w = -expf(v.w);
    aout[i] = o;
  }
}

// ---------------------------------------------------------------------------
// K1: in_proj (x half) via bf16 MFMA — 256x256 tile, BK=64, 512 thr / 8 waves
// (2M x 4N; per-wave 128x64 = 8x4 fragments). Counted-vmcnt 2-deep pipeline
// + T5 setprio around MFMA clusters + LDS-staged 2-panel epilogue.
// ---------------------------------------------------------------------------
__global__ __launch_bounds__(512, 2) void k_inproj_mfma(
    const ushort_t* __restrict__ Wb,   // [D_INNER][D_MODEL] bf16
    const ushort_t* __restrict__ HSb,  // [B][L][D_MODEL] bf16
    ushort_t* __restrict__ Cout) {     // [B][D_INNER][L] bf16
  // grid (8,8,4) = 256 blocks; XCD-aware bijective swizzle (256 % 8 == 0).
  const int flat = blockIdx.x + 8 * blockIdx.y + 64 * blockIdx.z;
  const int swz  = (flat & 7) * 32 + (flat >> 3);
  const int bn = swz & 7;
  const int bm = (swz >> 3) & 7;
  const int b  = swz >> 6;

  __shared__ ushort_t sh[65536];  // 128 KB
  const int tid  = threadIdx.x;
  const int w    = tid >> 6;
  const int lane = tid & 63;
  const int wm = w >> 2, wn = w & 3;
  const int ksel = lane >> 4;
  const int frow = lane & 15;
  const int sr = tid >> 2;        // staging row 0..127
  const int ss = tid & 3;         // staging slot 0..3

  const ushort_t* Ag = Wb + (size_t)(bm * 256) * D_MODEL;
  const ushort_t* Bg = HSb + (size_t)b * L_SEQ * D_MODEL
                           + (size_t)(bn * 256) * D_MODEL;

  f32x4 acc[8][4];
#pragma unroll
  for (int m = 0; m < 8; ++m)
#pragma unroll
    for (int n = 0; n < 4; ++n) acc[m][n] = (f32x4){0.f, 0.f, 0.f, 0.f};

  const int sxs = ss ^ ((sr >> 1) & 3);  // pre-swizzled global slot

  // 8 gl_lds per thread per K-tile: {A,B} x {half} x {ksub}.
#define STAGE(BUF, T)                                                            \
  do {                                                                           \
    _Pragma("unroll")                                                            \
    for (int mh = 0; mh < 4; ++mh) {                                             \
      const ushort_t* gbase = (mh < 2) ? Ag : Bg;                                \
      const ushort_t* grow = gbase + (size_t)((mh & 1) * 128 + sr) * D_MODEL     \
                                   + (T) * 64 + sxs * 8;                         \
      _Pragma("unroll")                                                          \
      for (int q = 0; q < 2; ++q) {                                              \
        ushort_t* dst = sh + (BUF) * 32768 + (mh >> 1) * 16384                   \
                           + (mh & 1) * 8192 + q * 4096 + tid * 8;               \
        __builtin_amdgcn_global_load_lds(                                        \
            (const __attribute__((address_space(1))) void*)(grow + q * 32),      \
            (__attribute__((address_space(3))) void*)dst, 16, 0, 0);             \
      }                                                                          \
    }                                                                            \
  } while (0)

#define COMPUTE(BUF)                                                             \
  do {                                                                           \
    _Pragma("unroll")                                                            \
    for (int ks = 0; ks < 2; ++ks) {                                             \
      bf16x8 af[8], bfr[4];                                                      \
      _Pragma("unroll")                                                          \
      for (int m = 0; m < 8; ++m) {                                              \
        int r = m * 16 + frow;                                                   \
        af[m] = *(const bf16x8*)(sh + (BUF) * 32768 + wm * 8192 + ks * 4096      \
                                 + (r * 4 + (ksel ^ ((r >> 1) & 3))) * 8);       \
      }                                                                          \
      _Pragma("unroll")                                                          \
      for (int n = 0; n < 4; ++n) {                                              \
        int ll = wn * 64 + n * 16 + frow;                                        \
        int h = ll >> 7, r = ll & 127;                                           \
        bfr[n] = *(const bf16x8*)(sh + (BUF) * 32768 + 16384 + h * 8192          \
                                  + ks * 4096                                    \
                                  + (r * 4 + (ksel ^ ((r >> 1) & 3))) * 8);      \
      }                                                                          \
      __builtin_amdgcn_s_setprio(1);                                             \
      _Pragma("unroll")                                                          \
      for (int m = 0; m < 8; ++m)                                                \
        _Pragma("unroll")                                                        \
        for (int n = 0; n < 4; ++n)                                              \
          acc[m][n] = __builtin_amdgcn_mfma_f32_16x16x32_bf16(af[m], bfr[n],     \
                                                              acc[m][n], 0, 0, 0); \
      __builtin_amdgcn_s_setprio(0);                                             \
    }                                                                            \
  } while (0)

  // ---- prologue: stage K-tiles 0,1 ----
  STAGE(0, 0);
  STAGE(1, 1);
  asm volatile("s_waitcnt vmcnt(8)" ::: "memory");  // tile 0 landed
  __builtin_amdgcn_s_barrier();

  // ---- main loop: 16 K-tiles total, 14 pipelined iterations ----
  for (int t = 0; t < 14; ++t) {
    COMPUTE(t & 1);
    __builtin_amdgcn_sched_barrier(0);
    __builtin_amdgcn_s_barrier();                    // buf[t&1] reads done
    STAGE(t & 1, t + 2);
    asm volatile("s_waitcnt vmcnt(8)" ::: "memory"); // tile t+1 landed
    __builtin_amdgcn_s_barrier();
    __builtin_amdgcn_sched_barrier(0);
  }
  COMPUTE(0);                                        // tile 14
  __builtin_amdgcn_sched_barrier(0);
  __builtin_amdgcn_s_barrier();
  asm volatile("s_waitcnt vmcnt(0)" ::: "memory");   // tile 15 landed
  __builtin_amdgcn_s_barrier();
  COMPUTE(1);                                        // tile 15
#undef STAGE
#undef COMPUTE

  __syncthreads();  // all LDS buffer reads done; reuse sh for epilogue

  // ---- epilogue: 2 panels of 128 rows via LDS [128][272], us8 stores ----
  const int crow0 = (lane >> 4) * 4;
  const int ccol  = lane & 15;
  ushort_t* Cb = Cout + (size_t)b * D_INNER * L_SEQ;
#pragma unroll
  for (int p = 0; p < 2; ++p) {
    if (wm == p) {
#pragma unroll
      for (int m = 0; m < 8; ++m)
#pragma unroll
        for (int n = 0; n < 4; ++n) {
          int r0 = m * 16 + crow0;
          int c  = wn * 64 + n * 16 + ccol;
#pragma unroll
          for (int i = 0; i < 4; ++i)
            sh[(r0 + i) * 272 + c] = f2bf(acc[m][n][i]);
        }
    }
    __syncthreads();
#pragma unroll
    for (int q = 0; q < 8; ++q) {
      int idx = q * 512 + tid;     // 4096 16B-chunks (128 rows x 32)
      int r   = idx >> 5;
      int c8  = idx & 31;
      us8 v = *(const us8*)(sh + r * 272 + c8 * 8);
      *(us8*)(Cb + (size_t)(bm * 256 + p * 128 + r) * L_SEQ + bn * 256 + c8 * 8) = v;
    }
    __syncthreads();
  }
}

// ---------------------------------------------------------------------------
// K3: x_proj via bf16 MFMA + fused conv4+SiLU. Split-K 4, N-tile 64,
// atomic epilogue (4-way contention) — the verified R12 configuration.
// Grid (ln=32, sk=4, b=4) = 512 blocks, 256 thr (4 waves 2x2: M 2x48, N 2x32).
// ---------------------------------------------------------------------------
__global__ __launch_bounds__(256) void k_xproj_fused(
    const ushort_t* __restrict__ XWb,  // [96][2048] bf16
    const ushort_t* __restrict__ Xpre, // [B][D_INNER][L] bf16 (pre-conv)
    const float* __restrict__ CW,      // [D_INNER][4] conv weights
    const float* __restrict__ CB,      // [D_INNER] conv bias
    float* __restrict__ Xout,          // [B][D_INNER][L] fp32 (post conv+silu)
    float* __restrict__ XDBL,          // [B][64][L] fp32 (atomic)
    float* __restrict__ OutB,          // [B][16][L]  (atomic)
    float* __restrict__ OutC) {        // [B][16][L]  (atomic)
  const int ln = blockIdx.x;   // 0..31 (l-tile of 64)
  const int sk = blockIdx.y;   // 0..3  (d-range of 512)
  const int b  = blockIdx.z;
  __shared__ ushort_t As[96 * 40];
  __shared__ ushort_t Bs[64 * 34];
  const int tid  = threadIdx.x;
  const int wv   = tid >> 6;
  const int lane = tid & 63;
  const int wr = wv >> 1, wc = wv & 1;
  const int ksel = lane >> 4;
  const int frow = lane & 15;

  f32x4 acc[3][2];
#pragma unroll
  for (int i = 0; i < 3; ++i)
#pragma unroll
    for (int j = 0; j < 2; ++j) acc[i][j] = (f32x4){0.f, 0.f, 0.f, 0.f};

  for (int k0 = 0; k0 < 512; k0 += 32) {
    const int koff = sk * 512 + k0;
    // ---- stage A tile [96][32] ----
    {
      int row = tid >> 2, s = tid & 3;
      bf16x8 v = *(const bf16x8*)(XWb + (size_t)row * D_INNER + koff + s * 8);
      *(bf16x8*)(As + row * 40 + s * 8) = v;
      if (tid < 128) {
        int row2 = 64 + (tid >> 2);
        bf16x8 v2 = *(const bf16x8*)(XWb + (size_t)row2 * D_INNER + koff + s * 8);
        *(bf16x8*)(As + row2 * 40 + s * 8) = v2;
      }
    }
    // ---- stage B tile [32 d][64 l]: 256 tasks, one per thread ----
    {
      int n4 = tid & 15;
      int kp = tid >> 4;
      int l0 = ln * 64 + 4 * n4;
      float sv[2][4];
#pragma unroll
      for (int r = 0; r < 2; ++r) {
        int d = koff + 2 * kp + r;
        const ushort_t* row = Xpre + ((size_t)b * D_INNER + d) * L_SEQ;
        ushort4 cur = *(const ushort4*)(row + l0);
        float em3 = 0.f, em2 = 0.f, em1 = 0.f;
        if (l0 >= 4) {
          ushort4 pv = *(const ushort4*)(row + l0 - 4);
          em3 = bf2f(pv.y); em2 = bf2f(pv.z); em1 = bf2f(pv.w);
        }
        float ee[7] = {em3, em2, em1, bf2f(cur.x), bf2f(cur.y), bf2f(cur.z), bf2f(cur.w)};
        float4 w = *(const float4*)(CW + d * 4);
        float bias = CB[d];
#pragma unroll
        for (int i = 0; i < 4; ++i) {
          float v = w.x * ee[i] + w.y * ee[i + 1] + w.z * ee[i + 2] + w.w * ee[i + 3] + bias;
          sv[r][i] = v / (1.f + expf(-v));
        }
        *(float4*)(Xout + ((size_t)b * D_INNER + d) * L_SEQ + l0) =
            make_float4(sv[r][0], sv[r][1], sv[r][2], sv[r][3]);
      }
#pragma unroll
      for (int i = 0; i < 4; ++i) {
        uint_t pk = (uint_t)f2bf(sv[0][i]) | ((uint_t)f2bf(sv[1][i]) << 16);
        *(uint_t*)(Bs + (4 * n4 + i) * 34 + 2 * kp) = pk;
      }
    }
    __syncthreads();

    // ---- fragments ----
    bf16x8 af[3], bfr[2];
#pragma unroll
    for (int mi = 0; mi < 3; ++mi) {
      int row = wr * 48 + mi * 16 + frow;
      af[mi] = *(const bf16x8*)(As + row * 40 + ksel * 8);
    }
#pragma unroll
    for (int ni = 0; ni < 2; ++ni) {
      int n = wc * 32 + ni * 16 + frow;
      const uint_t* p = (const uint_t*)(Bs + n * 34);
      union { uint_t u[4]; bf16x8 v; } fr;
#pragma unroll
      for (int q = 0; q < 4; ++q) fr.u[q] = p[ksel * 4 + q];
      bfr[ni] = fr.v;
    }
#pragma unroll
    for (int mi = 0; mi < 3; ++mi)
#pragma unroll
      for (int ni = 0; ni < 2; ++ni)
        acc[mi][ni] = __builtin_amdgcn_mfma_f32_16x16x32_bf16(af[mi], bfr[ni], acc[mi][ni], 0, 0, 0);
    __syncthreads();
  }

  // ---- epilogue: atomic accumulate (4-way contention) ----
  const int crow0 = (lane >> 4) * 4;
  const int ccol  = lane & 15;
#pragma unroll
  for (int mi = 0; mi < 3; ++mi) {
    int e0 = wr * 48 + mi * 16 + crow0;
    float* base;
    int eoff;
    if (e0 < 64)      { base = XDBL + (size_t)b * 64 * L_SEQ; eoff = e0; }
    else if (e0 < 80) { base = OutB + (size_t)b * D_STATE * L_SEQ; eoff = e0 - 64; }
    else              { base = OutC + (size_t)b * D_STATE * L_SEQ; eoff = e0 - 80; }
#pragma unroll
    for (int ni = 0; ni < 2; ++ni) {
      int l = ln * 64 + wc * 32 + ni * 16 + ccol;
#pragma unroll
      for (int r = 0; r < 4; ++r)
        atomicAdd(base + (size_t)(eoff + r) * L_SEQ + l, acc[mi][ni][r]);
    }
  }
}

// ---------------------------------------------------------------------------
// K4: dt GEMM via bf16 MFMA. DT[b][d][l] = sum_r DW[d][r] * XDBL[b][r][l].
// K=64 single-stage; 128x128 tile; 4 waves (2x2); write-bound epilogue.
// ---------------------------------------------------------------------------
__global__ __launch_bounds__(256) void k_dt_mfma(
    const ushort_t* __restrict__ DWb,  // [D_INNER][64] bf16
    const float* __restrict__ XDBL,    // [B][64][L] fp32
    float* __restrict__ DT) {          // [B][D_INNER][L] fp32
  const int ln = blockIdx.x;
  const int dm = blockIdx.y;
  const int b  = blockIdx.z;
  __shared__ ushort_t As[128 * 72];
  __shared__ ushort_t Bs[128 * 68];
  const int tid  = threadIdx.x;
  const int wv   = tid >> 6;
  const int lane = tid & 63;
  const int wr = wv >> 1, wc = wv & 1;
  const int ksel = lane >> 4;
  const int frow = lane & 15;

#pragma unroll
  for (int q = 0; q < 4; ++q) {
    int u = tid + 256 * q;
    int row = u >> 3, s = u & 7;
    *(bf16x8*)(As + row * 72 + s * 8) =
        *(const bf16x8*)(DWb + (size_t)(dm * 128 + row) * DT_RANK + s * 8);
  }
#pragma unroll
  for (int q = 0; q < 4; ++q) {
    int u = tid + 256 * q;
    int n4 = u & 31;
    int kp = u >> 5;
    const float* g = XDBL + ((size_t)b * DT_RANK + 2 * kp) * L_SEQ + ln * 128 + 4 * n4;
    float4 x0 = *(const float4*)g;
    float4 x1 = *(const float4*)(g + L_SEQ);
    float e0[4] = {x0.x, x0.y, x0.z, x0.w};
    float e1[4] = {x1.x, x1.y, x1.z, x1.w};
#pragma unroll
    for (int i = 0; i < 4; ++i) {
      uint_t pk = (uint_t)f2bf(e0[i]) | ((uint_t)f2bf(e1[i]) << 16);
      *(uint_t*)(Bs + (4 * n4 + i) * 68 + 2 * kp) = pk;
    }
  }
  __syncthreads();

  f32x4 acc[4][4];
#pragma unroll
  for (int i = 0; i < 4; ++i)
#pragma unroll
    for (int j = 0; j < 4; ++j) acc[i][j] = (f32x4){0.f, 0.f, 0.f, 0.f};

#pragma unroll
  for (int ks = 0; ks < 2; ++ks) {
    bf16x8 af[4], bfr[4];
#pragma unroll
    for (int m = 0; m < 4; ++m) {
      int row = wr * 64 + m * 16 + frow;
      af[m] = *(const bf16x8*)(As + row * 72 + ks * 32 + ksel * 8);
    }
#pragma unroll
    for (int n = 0; n < 4; ++n) {
      int nn = wc * 64 + n * 16 + frow;
      bfr[n] = *(const bf16x8*)(Bs + nn * 68 + ks * 32 + ksel * 8);
    }
#pragma unroll
    for (int m = 0; m < 4; ++m)
#pragma unroll
      for (int n = 0; n < 4; ++n)
        acc[m][n] = __builtin_amdgcn_mfma_f32_16x16x32_bf16(af[m], bfr[n], acc[m][n], 0, 0, 0);
  }

  const int crow0 = (lane >> 4) * 4;
  const int ccol  = lane & 15;
  float* Cb = DT + (size_t)b * D_INNER * L_SEQ;
#pragma unroll
  for (int m = 0; m < 4; ++m) {
    int gr0 = dm * 128 + wr * 64 + m * 16 + crow0;
#pragma unroll
    for (int n = 0; n < 4; ++n) {
      int gc = ln * 128 + wc * 64 + n * 16 + ccol;
#pragma unroll
      for (int i = 0; i < 4; ++i)
        Cb[(size_t)(gr0 + i) * L_SEQ + gc] = acc[m][n][i];
    }
  }
}

extern "C" void kernel_launch(void* const* d_in, const int* in_sizes, int n_in,
                              void* d_out, int out_size, void* d_ws, size_t ws_size,
                              hipStream_t stream) {
  const float* hs   = (const float*)d_in[0];
  const float* ipw  = (const float*)d_in[1];
  const float* cw   = (const float*)d_in[2];
  const float* cb   = (const float*)d_in[3];
  const float* xpw  = (const float*)d_in[4];
  const float* dpw  = (const float*)d_in[5];
  const float* alog = (const float*)d_in[6];

  float* out    = (float*)d_out;
  float* dt_out = out + OFF_DT;
  float* a_out  = out + OFF_A;
  float* b_out  = out + OFF_B;
  float* c_out  = out + OFF_C;
  float* x_out  = out + OFF_X;

  // Scratch plan:
  //  - bf16 HS (16.8 MB) + bf16 W-half (4.2 MB) in x region of d_out (dead
  //    after k_inproj; k_xproj_fused overwrites x region afterwards).
  //  - xpre (pre-conv x, bf16, 33.5 MB) in dt region (dead after xproj;
  //    k_dt_mfma overwrites).
  //  - d_ws: xdbl fp32 (2 MB) | XWb bf16 (384 KB) | DWb bf16 (256 KB).
  unsigned short* bfHS = (unsigned short*)x_out;
  unsigned short* bfW  = bfHS + (size_t)B_SZ * L_SEQ * D_MODEL;
  unsigned short* xpre = (unsigned short*)dt_out;
  float* xdbl = (float*)d_ws;
  unsigned short* xwb = (unsigned short*)((char*)d_ws + 2097152);
  unsigned short* dwb = (unsigned short*)((char*)d_ws + 2097152 + 393216);

  // One fused prep launch: 4 casts + zero xdbl + zero B|C + A = -exp(A_log).
  k_prep<<<dim3((N4_TOT + 255) / 256), 256, 0, stream>>>(
      (const float4*)hs, (const float4*)ipw, (const float4*)xpw,
      (const float4*)dpw, (const float4*)alog,
      (ushort4*)bfHS, (ushort4*)bfW, (ushort4*)xwb, (ushort4*)dwb,
      (float4*)xdbl, (float4*)b_out, (float4*)a_out);

  k_inproj_mfma<<<dim3(8, 8, 4), 512, 0, stream>>>(bfW, bfHS, xpre);
  k_xproj_fused<<<dim3(32, 4, 4), 256, 0, stream>>>(xwb, xpre, cw, cb,
                                                    x_out, xdbl, b_out, c_out);
  k_dt_mfma<<<dim3(16, 16, 4), 256, 0, stream>>>(dwb, xdbl, dt_out);
}